// Round 1
// baseline (1010.132 us; speedup 1.0000x reference)
//
#include <hip/hip_runtime.h>
#include <stdint.h>

#define N_ 8192
#define M_ 4096
#define FIN_ 256
#define F_ 128
#define B_ 2048

typedef __attribute__((ext_vector_type(8))) short vs8;
typedef __attribute__((ext_vector_type(8))) __bf16 vb8;
typedef __attribute__((ext_vector_type(4))) float vf4;

union ABu { vs8 s; vb8 b; };

__device__ __forceinline__ vf4 mfma16(const ABu& a, const ABu& b, vf4 c) {
    return __builtin_amdgcn_mfma_f32_16x16x32_bf16(a.b, b.b, c, 0, 0, 0);
}
__device__ __forceinline__ unsigned short f2b(float x) {
    union { float f; unsigned u; } v; v.f = x;
    unsigned r = v.u + 0x7fffu + ((v.u >> 16) & 1u);
    return (unsigned short)(r >> 16);
}
__device__ __forceinline__ float lrelu(float x) { return x > 0.f ? x : 0.2f * x; }

// ---------------- small prep: W[256][128] f32 -> WT[128][256] bf16 ----------------
__global__ void k_wprep(const float* __restrict__ W1, const float* __restrict__ W2,
                        unsigned short* __restrict__ W1T, unsigned short* __restrict__ W2T) {
    int id = blockIdx.x * 256 + threadIdx.x;            // 0..65535
    const float* W = (id < 32768) ? W1 : W2;
    unsigned short* WT = (id < 32768) ? W1T : W2T;
    int o = id & 32767;
    int f = o >> 8, k = o & 255;
    WT[o] = f2b(W[k * F_ + f]);
}

// ---------------- h = X[rows][256] @ W  (via WT bf16), out f32 [rows][128] ----------------
__global__ __launch_bounds__(256) void k_hgemm(const float* __restrict__ X,
                                               const unsigned short* __restrict__ WT,
                                               float* __restrict__ H) {
    int w = threadIdx.x >> 6, l = threadIdx.x & 63;
    int lr = l & 15, lg = l >> 4;
    int rbase = blockIdx.x * 32 + (w >> 1) * 16;
    int fbase = (w & 1) * 64;
    vf4 acc[4] = {};
    const float* xp = X + (size_t)(rbase + lr) * FIN_ + lg * 8;
    for (int kk = 0; kk < FIN_; kk += 32) {
        ABu af;
#pragma unroll
        for (int j = 0; j < 8; ++j) af.s[j] = (short)f2b(xp[kk + j]);
#pragma unroll
        for (int q = 0; q < 4; ++q) {
            int col = fbase + q * 16 + lr;
            ABu bf; bf.s = *(const vs8*)(WT + col * FIN_ + kk + lg * 8);
            acc[q] = mfma16(af, bf, acc[q]);
        }
    }
#pragma unroll
    for (int q = 0; q < 4; ++q)
#pragma unroll
        for (int r = 0; r < 4; ++r) {
            int row = blockIdx.x * 32 + (w >> 1) * 16 + lg * 4 + r;
            int col = fbase + q * 16 + lr;
            H[(size_t)row * F_ + col] = acc[q][r];
        }
}

// ---------------- h f32 [rows][128] -> hT bf16 [128][rows] ----------------
__global__ void k_castT(const float* __restrict__ Hsrc, unsigned short* __restrict__ HT, int rows) {
    __shared__ float tile[32][33];
    int r0 = blockIdx.x * 32, f0 = blockIdx.y * 32;
    int tx = threadIdx.x & 31, ty = threadIdx.x >> 5;   // 32 x 8
#pragma unroll
    for (int p = 0; p < 4; ++p)
        tile[ty + p * 8][tx] = Hsrc[(size_t)(r0 + ty + p * 8) * F_ + f0 + tx];
    __syncthreads();
#pragma unroll
    for (int p = 0; p < 4; ++p)
        HT[(size_t)(f0 + ty + p * 8) * rows + r0 + tx] = f2b(tile[tx][ty + p * 8]);
}

// ---------------- s1[m]=h1[m]·a[:128], s2[n]=h2[n]·a[128:] ----------------
__global__ void k_svec(const float* __restrict__ h1, const float* __restrict__ h2,
                       const float* __restrict__ a, float* __restrict__ s1, float* __restrict__ s2) {
    int w = threadIdx.x >> 6, l = threadIdx.x & 63;
    int row = blockIdx.x * 4 + w;                        // 0..12287
    const float* hp; const float* ap; float* sp;
    if (row < M_) { hp = h1 + (size_t)row * F_; ap = a;       sp = s1 + row; }
    else { int r = row - M_; hp = h2 + (size_t)r * F_; ap = a + F_; sp = s2 + r; }
    float v = hp[l] * ap[l] + hp[64 + l] * ap[64 + l];
    for (int off = 32; off > 0; off >>= 1) v += __shfl_down(v, off, 64);
    if (l == 0) *sp = v;
}

// ---------------- gather h2wT[f][b] = bf16(h2[src[b]][f]) ----------------
__global__ void k_gather(const float* __restrict__ h2, const int* __restrict__ src,
                         unsigned short* __restrict__ h2wT) {
    int b = blockIdx.x;                                  // 2048
    int f = threadIdx.x;                                 // 128
    float v = h2[(size_t)src[b] * F_ + f];
    h2wT[(size_t)f * B_ + b] = f2b(v);
}

// ---------------- w3[b]=1/rowcount(city[src[b]]), w4 for prov ----------------
__global__ __launch_bounds__(256) void k_counts(const int* __restrict__ city, const int* __restrict__ prov,
                                                const int* __restrict__ src,
                                                float* __restrict__ w3, float* __restrict__ w4) {
    __shared__ int red[256];
    int b = blockIdx.x & (B_ - 1);
    const int* adj = (blockIdx.x < B_) ? city : prov;
    float* wout = (blockIdx.x < B_) ? w3 : w4;
    const int* rowp = adj + (size_t)src[b] * N_;
    int t = threadIdx.x, cnt = 0;
    for (int i = t * 4; i < N_; i += 1024) {
        int4 v = *(const int4*)(rowp + i);
        cnt += (v.x > 0) + (v.y > 0) + (v.z > 0) + (v.w > 0);
    }
    red[t] = cnt; __syncthreads();
    for (int s = 128; s > 0; s >>= 1) { if (t < s) red[t] += red[t + s]; __syncthreads(); }
    if (t == 0) wout[b] = red[0] > 0 ? 1.0f / (float)red[0] : 0.0f;
}

// ---------------- per-row of inter_adj: bitmask + softmax row stats ----------------
__global__ __launch_bounds__(256) void k_adjstats(const int* __restrict__ adj, const float* __restrict__ s1,
                                                  const float* __restrict__ s2, unsigned short* __restrict__ bm,
                                                  float* __restrict__ rowmax, float* __restrict__ rowinv) {
    __shared__ float red[256];
    int n = blockIdx.x, t = threadIdx.x;
    const int* rp = adj + (size_t)n * M_ + t * 16;
    float sv[16]; unsigned mask = 0;
#pragma unroll
    for (int c = 0; c < 4; ++c) {
        int4 v = *(const int4*)(rp + c * 4);
        if (v.x > 0) mask |= 1u << (c * 4 + 0);
        if (v.y > 0) mask |= 1u << (c * 4 + 1);
        if (v.z > 0) mask |= 1u << (c * 4 + 2);
        if (v.w > 0) mask |= 1u << (c * 4 + 3);
        float4 s = *(const float4*)(s1 + t * 16 + c * 4);
        sv[c * 4 + 0] = s.x; sv[c * 4 + 1] = s.y; sv[c * 4 + 2] = s.z; sv[c * 4 + 3] = s.w;
    }
    bm[(size_t)n * 256 + t] = (unsigned short)(mask & 0xffffu);
    float mx = -3.0e38f;
#pragma unroll
    for (int j = 0; j < 16; ++j) if (mask & (1u << j)) mx = fmaxf(mx, sv[j]);
    red[t] = mx; __syncthreads();
    for (int s = 128; s > 0; s >>= 1) { if (t < s) red[t] = fmaxf(red[t], red[t + s]); __syncthreads(); }
    float s1mx = red[0];
    __syncthreads();
    float s2n = s2[n];
    float rmx = lrelu(s2n + s1mx);
    float sum = 0.f;
#pragma unroll
    for (int j = 0; j < 16; ++j) if (mask & (1u << j)) sum += __expf(lrelu(s2n + sv[j]) - rmx);
    red[t] = sum; __syncthreads();
    for (int s = 128; s > 0; s >>= 1) { if (t < s) red[t] += red[t + s]; __syncthreads(); }
    if (t == 0) {
        bool any = s1mx > -2.9e38f;
        rowmax[n] = any ? rmx : 0.f;
        rowinv[n] = (any && red[0] > 0.f) ? 1.0f / red[0] : 0.f;
    }
}

// ---------------- materialize att bf16 [N][M] ----------------
__global__ __launch_bounds__(256) void k_attmat(const unsigned char* __restrict__ bm8,
                                                const float* __restrict__ s1, const float* __restrict__ s2,
                                                const float* __restrict__ rowmax, const float* __restrict__ rowinv,
                                                unsigned short* __restrict__ att) {
    int id = blockIdx.x * 256 + threadIdx.x;             // N*M/8 threads
    int n = id >> 9;
    int m = (id & 511) * 8;
    unsigned bits = bm8[(size_t)n * 512 + (m >> 3)];
    float s2n = s2[n], rmx = rowmax[n], rin = rowinv[n];
    float4 sa = *(const float4*)(s1 + m);
    float4 sb = *(const float4*)(s1 + m + 4);
    float sv[8] = {sa.x, sa.y, sa.z, sa.w, sb.x, sb.y, sb.z, sb.w};
    vs8 o;
#pragma unroll
    for (int j = 0; j < 8; ++j) {
        float v = (bits & (1u << j)) ? __expf(lrelu(s2n + sv[j]) - rmx) * rin : 0.f;
        o[j] = (short)f2b(v);
    }
    *(vs8*)(att + (size_t)n * M_ + m) = o;
}

// ---------------- u_in += att @ h1  (B from h1T) ----------------
__global__ __launch_bounds__(256) void k_gemmA(const unsigned short* __restrict__ att,
                                               const unsigned short* __restrict__ h1T,
                                               float* __restrict__ u_in) {
    int w = threadIdx.x >> 6, l = threadIdx.x & 63;
    int lr = l & 15, lg = l >> 4;
    int nb = blockIdx.x * 32 + (w >> 1) * 16;
    int fb = (w & 1) * 64;
    vf4 acc[4] = {};
    const unsigned short* ap = att + (size_t)(nb + lr) * M_ + lg * 8;
    int m0s = blockIdx.y * 2048;
    for (int m0 = m0s; m0 < m0s + 2048; m0 += 32) {
        ABu af; af.s = *(const vs8*)(ap + m0);
#pragma unroll
        for (int q = 0; q < 4; ++q) {
            ABu bf; bf.s = *(const vs8*)(h1T + (size_t)(fb + q * 16 + lr) * M_ + m0 + lg * 8);
            acc[q] = mfma16(af, bf, acc[q]);
        }
    }
#pragma unroll
    for (int q = 0; q < 4; ++q)
#pragma unroll
        for (int r = 0; r < 4; ++r)
            atomicAdd(&u_in[(size_t)(blockIdx.x * 32 + (w >> 1) * 16 + lg * 4 + r) * F_ + fb + q * 16 + lr],
                      acc[q][r]);
}

// ---------------- v_in += att.T @ h2  (B from h2T) ----------------
__global__ __launch_bounds__(256) void k_gemmB(const unsigned short* __restrict__ att,
                                               const unsigned short* __restrict__ h2T,
                                               float* __restrict__ v_in) {
    int w = threadIdx.x >> 6, l = threadIdx.x & 63;
    int lr = l & 15, lg = l >> 4;
    int mb = blockIdx.x * 16;
    int fb = w * 32;
    vf4 acc[2] = {};
    int n0s = blockIdx.y * 2048;
    for (int n0 = n0s; n0 < n0s + 2048; n0 += 32) {
        ABu af;
#pragma unroll
        for (int j = 0; j < 8; ++j)
            af.s[j] = (short)att[(size_t)(n0 + lg * 8 + j) * M_ + mb + lr];
#pragma unroll
        for (int q = 0; q < 2; ++q) {
            ABu bf; bf.s = *(const vs8*)(h2T + (size_t)(fb + q * 16 + lr) * N_ + n0 + lg * 8);
            acc[q] = mfma16(af, bf, acc[q]);
        }
    }
#pragma unroll
    for (int q = 0; q < 2; ++q)
#pragma unroll
        for (int r = 0; r < 4; ++r)
            atomicAdd(&v_in[(size_t)(mb + lg * 4 + r) * F_ + fb + q * 16 + lr], acc[q][r]);
}

// ---------------- u_in += (cmask/c3 + pmask/c4).T @ h2[src]  (B from h2wT) ----------------
__global__ __launch_bounds__(256) void k_gemmC(const int* __restrict__ city, const int* __restrict__ prov,
                                               const int* __restrict__ src, const float* __restrict__ w3,
                                               const float* __restrict__ w4,
                                               const unsigned short* __restrict__ h2wT,
                                               float* __restrict__ u_in) {
    int w = threadIdx.x >> 6, l = threadIdx.x & 63;
    int lr = l & 15, lg = l >> 4;
    int nb = blockIdx.x * 16;
    int fb = w * 32;
    int n = nb + lr;
    vf4 acc[2] = {};
    for (int b0 = 0; b0 < B_; b0 += 32) {
        ABu af;
#pragma unroll
        for (int j = 0; j < 8; ++j) {
            int b = b0 + lg * 8 + j;
            int sb = src[b];
            float v = 0.f;
            if (city[(size_t)sb * N_ + n] > 0) v += w3[b];
            if (prov[(size_t)sb * N_ + n] > 0) v += w4[b];
            af.s[j] = (short)f2b(v);
        }
#pragma unroll
        for (int q = 0; q < 2; ++q) {
            ABu bf; bf.s = *(const vs8*)(h2wT + (size_t)(fb + q * 16 + lr) * B_ + b0 + lg * 8);
            acc[q] = mfma16(af, bf, acc[q]);
        }
    }
#pragma unroll
    for (int q = 0; q < 2; ++q)
#pragma unroll
        for (int r = 0; r < 4; ++r)
            atomicAdd(&u_in[(size_t)(nb + lg * 4 + r) * F_ + fb + q * 16 + lr], acc[q][r]);
}

// ---------------- batchnorm column stats (sum, sumsq) ----------------
__global__ __launch_bounds__(256) void k_bnstats(const float* __restrict__ P, int R,
                                                 float* __restrict__ sum, float* __restrict__ sq) {
    __shared__ float r1[256], r2[256];
    int f = threadIdx.x & 127;
    int half = threadIdx.x >> 7;
    float s = 0.f, s2v = 0.f;
    for (int r = blockIdx.x * 2 + half; r < R; r += gridDim.x * 2) {
        float v = P[(size_t)r * F_ + f];
        s += v; s2v += v * v;
    }
    r1[threadIdx.x] = s; r2[threadIdx.x] = s2v;
    __syncthreads();
    if (half == 0) {
        atomicAdd(&sum[f], r1[f] + r1[f + 128]);
        atomicAdd(&sq[f], r2[f] + r2[f + 128]);
    }
}

// ---------------- scale/shift from stats ----------------
__global__ void k_bnfinal(const float* __restrict__ stats, const float* __restrict__ g1,
                          const float* __restrict__ b1, const float* __restrict__ g2,
                          const float* __restrict__ b2, float* __restrict__ scsh) {
    int t = threadIdx.x;                                  // 256
    int f = t & 127;
    const float* sum; const float* sq; const float* g; const float* be; float R; float* sc; float* sh;
    if (t < 128) { sum = stats;       sq = stats + 128; g = g1; be = b1; R = 4096.f; sc = scsh;       sh = scsh + 128; }
    else         { sum = stats + 256; sq = stats + 384; g = g2; be = b2; R = 8192.f; sc = scsh + 256; sh = scsh + 384; }
    float mean = sum[f] / R;
    float var = sq[f] / R - mean * mean;
    float s = g[f] * rsqrtf(var + 1e-5f);
    sc[f] = s; sh[f] = be[f] - mean * s;
}

// ---------------- apply bn + leaky + cast bf16 ----------------
__global__ void k_bnapply(const float* __restrict__ P, const float* __restrict__ scsh, int which,
                          unsigned short* __restrict__ Q) {
    int id = blockIdx.x * 256 + threadIdx.x;
    int f = id & 127;
    float s = scsh[which * 256 + f], sh = scsh[which * 256 + 128 + f];
    Q[id] = f2b(lrelu(P[id] * s + sh));
}

// ---------------- out = elu(U @ V^T) ----------------
__global__ __launch_bounds__(256) void k_gemmD(const unsigned short* __restrict__ U,
                                               const unsigned short* __restrict__ V,
                                               float* __restrict__ out) {
    int w = threadIdx.x >> 6, l = threadIdx.x & 63;
    int lr = l & 15, lg = l >> 4;
    int nb = blockIdx.x * 64 + w * 16;
    int mb = blockIdx.y * 64;
    vf4 acc[4] = {};
#pragma unroll
    for (int k0 = 0; k0 < F_; k0 += 32) {
        ABu af; af.s = *(const vs8*)(U + (size_t)(nb + lr) * F_ + k0 + lg * 8);
#pragma unroll
        for (int q = 0; q < 4; ++q) {
            ABu bf; bf.s = *(const vs8*)(V + (size_t)(mb + q * 16 + lr) * F_ + k0 + lg * 8);
            acc[q] = mfma16(af, bf, acc[q]);
        }
    }
#pragma unroll
    for (int q = 0; q < 4; ++q)
#pragma unroll
        for (int r = 0; r < 4; ++r) {
            int row = nb + lg * 4 + r;
            int col = mb + q * 16 + lr;
            float x = acc[q][r];
            out[(size_t)row * M_ + col] = x > 0.f ? x : __expf(x) - 1.f;
        }
}

extern "C" void kernel_launch(void* const* d_in, const int* in_sizes, int n_in,
                              void* d_out, int out_size, void* d_ws, size_t ws_size,
                              hipStream_t stream) {
    const float* Sinput = (const float*)d_in[0];
    const float* Rinput = (const float*)d_in[1];
    const int* inter_adj = (const int*)d_in[2];
    const int* city_adj = (const int*)d_in[3];
    const int* prov_adj = (const int*)d_in[4];
    const int* src = (const int*)d_in[5];
    const float* W1 = (const float*)d_in[6];
    const float* W2 = (const float*)d_in[7];
    const float* a = (const float*)d_in[8];
    const float* g1 = (const float*)d_in[11];
    const float* b1 = (const float*)d_in[12];
    const float* g2 = (const float*)d_in[13];
    const float* b2 = (const float*)d_in[14];
    float* out = (float*)d_out;

    char* ws = (char*)d_ws;
    size_t o = 0;
    auto take = [&](size_t bytes) { char* p = ws + o; o += (bytes + 255) & ~(size_t)255; return p; };
    float* u_in = (float*)take((size_t)N_ * F_ * 4);
    float* v_in = (float*)take((size_t)M_ * F_ * 4);
    float* stats = (float*)take(512 * 4);
    size_t zero_bytes = o;                               // u_in + v_in + stats zeroed each launch
    float* h1 = (float*)take((size_t)M_ * F_ * 4);
    float* h2 = (float*)take((size_t)N_ * F_ * 4);
    unsigned short* h1T = (unsigned short*)take((size_t)F_ * M_ * 2);
    unsigned short* h2T = (unsigned short*)take((size_t)F_ * N_ * 2);
    unsigned short* W1T = (unsigned short*)take((size_t)F_ * FIN_ * 2);
    unsigned short* W2T = (unsigned short*)take((size_t)F_ * FIN_ * 2);
    float* s1 = (float*)take(M_ * 4);
    float* s2 = (float*)take(N_ * 4);
    float* rowmax = (float*)take(N_ * 4);
    float* rowinv = (float*)take(N_ * 4);
    float* w3 = (float*)take(B_ * 4);
    float* w4 = (float*)take(B_ * 4);
    unsigned short* h2wT = (unsigned short*)take((size_t)F_ * B_ * 2);
    float* scsh = (float*)take(512 * 4);
    unsigned short* u_outb = (unsigned short*)take((size_t)N_ * F_ * 2);
    unsigned short* v_outb = (unsigned short*)take((size_t)M_ * F_ * 2);
    unsigned short* bm = (unsigned short*)take((size_t)N_ * 256 * 2);
    unsigned short* att = (unsigned short*)take((size_t)N_ * M_ * 2);
    (void)ws_size; (void)in_sizes; (void)n_in; (void)out_size;

    hipMemsetAsync(d_ws, 0, zero_bytes, stream);

    k_wprep<<<256, 256, 0, stream>>>(W1, W2, W1T, W2T);
    k_hgemm<<<M_ / 32, 256, 0, stream>>>(Rinput, W1T, h1);
    k_hgemm<<<N_ / 32, 256, 0, stream>>>(Sinput, W2T, h2);
    k_castT<<<dim3(M_ / 32, 4), 256, 0, stream>>>(h1, h1T, M_);
    k_castT<<<dim3(N_ / 32, 4), 256, 0, stream>>>(h2, h2T, N_);
    k_svec<<<(M_ + N_) / 4, 256, 0, stream>>>(h1, h2, a, s1, s2);
    k_gather<<<B_, 128, 0, stream>>>(h2, src, h2wT);
    k_counts<<<2 * B_, 256, 0, stream>>>(city_adj, prov_adj, src, w3, w4);
    k_adjstats<<<N_, 256, 0, stream>>>(inter_adj, s1, s2, bm, rowmax, rowinv);
    k_attmat<<<(size_t)N_ * M_ / 8 / 256, 256, 0, stream>>>((const unsigned char*)bm, s1, s2, rowmax, rowinv, att);
    k_gemmA<<<dim3(N_ / 32, 2), 256, 0, stream>>>(att, h1T, u_in);
    k_gemmB<<<dim3(M_ / 16, 4), 256, 0, stream>>>(att, h2T, v_in);
    k_gemmC<<<N_ / 16, 256, 0, stream>>>(city_adj, prov_adj, src, w3, w4, h2wT, u_in);
    k_bnstats<<<128, 256, 0, stream>>>(v_in, M_, stats, stats + 128);
    k_bnstats<<<128, 256, 0, stream>>>(u_in, N_, stats + 256, stats + 384);
    k_bnfinal<<<1, 256, 0, stream>>>(stats, g1, b1, g2, b2, scsh);
    k_bnapply<<<M_ * F_ / 256, 256, 0, stream>>>(v_in, scsh, 0, v_outb);
    k_bnapply<<<N_ * F_ / 256, 256, 0, stream>>>(u_in, scsh, 1, u_outb);
    k_gemmD<<<dim3(N_ / 64, M_ / 64), 256, 0, stream>>>(u_outb, v_outb, out);
}

// Round 2
// 618.291 us; speedup vs baseline: 1.6337x; 1.6337x over previous
//
#include <hip/hip_runtime.h>
#include <stdint.h>

#define N_ 8192
#define M_ 4096
#define FIN_ 256
#define F_ 128
#define B_ 2048

typedef __attribute__((ext_vector_type(8))) short vs8;
typedef __attribute__((ext_vector_type(8))) __bf16 vb8;
typedef __attribute__((ext_vector_type(4))) float vf4;

union ABu { vs8 s; vb8 b; };

__device__ __forceinline__ vf4 mfma16(const ABu& a, const ABu& b, vf4 c) {
    return __builtin_amdgcn_mfma_f32_16x16x32_bf16(a.b, b.b, c, 0, 0, 0);
}
__device__ __forceinline__ unsigned short f2b(float x) {
    union { float f; unsigned u; } v; v.f = x;
    unsigned r = v.u + 0x7fffu + ((v.u >> 16) & 1u);
    return (unsigned short)(r >> 16);
}
__device__ __forceinline__ float lrelu(float x) { return x > 0.f ? x : 0.2f * x; }

// ---------------- small prep: W[256][128] f32 -> WT[128][256] bf16 ----------------
__global__ void k_wprep(const float* __restrict__ W1, const float* __restrict__ W2,
                        unsigned short* __restrict__ W1T, unsigned short* __restrict__ W2T) {
    int id = blockIdx.x * 256 + threadIdx.x;            // 0..65535
    const float* W = (id < 32768) ? W1 : W2;
    unsigned short* WT = (id < 32768) ? W1T : W2T;
    int o = id & 32767;
    int f = o >> 8, k = o & 255;
    WT[o] = f2b(W[k * F_ + f]);
}

// ---------------- h = X[rows][256] @ W  (via WT bf16), out f32 [rows][128] ----------------
__global__ __launch_bounds__(256) void k_hgemm(const float* __restrict__ X,
                                               const unsigned short* __restrict__ WT,
                                               float* __restrict__ H) {
    int w = threadIdx.x >> 6, l = threadIdx.x & 63;
    int lr = l & 15, lg = l >> 4;
    int rbase = blockIdx.x * 32 + (w >> 1) * 16;
    int fbase = (w & 1) * 64;
    vf4 acc[4] = {};
    const float* xp = X + (size_t)(rbase + lr) * FIN_ + lg * 8;
    for (int kk = 0; kk < FIN_; kk += 32) {
        ABu af;
#pragma unroll
        for (int j = 0; j < 8; ++j) af.s[j] = (short)f2b(xp[kk + j]);
#pragma unroll
        for (int q = 0; q < 4; ++q) {
            int col = fbase + q * 16 + lr;
            ABu bf; bf.s = *(const vs8*)(WT + col * FIN_ + kk + lg * 8);
            acc[q] = mfma16(af, bf, acc[q]);
        }
    }
#pragma unroll
    for (int q = 0; q < 4; ++q)
#pragma unroll
        for (int r = 0; r < 4; ++r) {
            int row = blockIdx.x * 32 + (w >> 1) * 16 + lg * 4 + r;
            int col = fbase + q * 16 + lr;
            H[(size_t)row * F_ + col] = acc[q][r];
        }
}

// ---------------- h f32 [rows][128] -> hT bf16 [128][rows] ----------------
__global__ void k_castT(const float* __restrict__ Hsrc, unsigned short* __restrict__ HT, int rows) {
    __shared__ float tile[32][33];
    int r0 = blockIdx.x * 32, f0 = blockIdx.y * 32;
    int tx = threadIdx.x & 31, ty = threadIdx.x >> 5;   // 32 x 8
#pragma unroll
    for (int p = 0; p < 4; ++p)
        tile[ty + p * 8][tx] = Hsrc[(size_t)(r0 + ty + p * 8) * F_ + f0 + tx];
    __syncthreads();
#pragma unroll
    for (int p = 0; p < 4; ++p)
        HT[(size_t)(f0 + ty + p * 8) * rows + r0 + tx] = f2b(tile[tx][ty + p * 8]);
}

// ---------------- s1[m]=h1[m]·a[:128], s2[n]=h2[n]·a[128:] ----------------
__global__ void k_svec(const float* __restrict__ h1, const float* __restrict__ h2,
                       const float* __restrict__ a, float* __restrict__ s1, float* __restrict__ s2) {
    int w = threadIdx.x >> 6, l = threadIdx.x & 63;
    int row = blockIdx.x * 4 + w;                        // 0..12287
    const float* hp; const float* ap; float* sp;
    if (row < M_) { hp = h1 + (size_t)row * F_; ap = a;       sp = s1 + row; }
    else { int r = row - M_; hp = h2 + (size_t)r * F_; ap = a + F_; sp = s2 + r; }
    float v = hp[l] * ap[l] + hp[64 + l] * ap[64 + l];
    for (int off = 32; off > 0; off >>= 1) v += __shfl_down(v, off, 64);
    if (l == 0) *sp = v;
}

// ---------------- gather h2wT[f][b] = bf16(h2[src[b]][f]) ----------------
__global__ void k_gather(const float* __restrict__ h2, const int* __restrict__ src,
                         unsigned short* __restrict__ h2wT) {
    int b = blockIdx.x;                                  // 2048
    int f = threadIdx.x;                                 // 128
    float v = h2[(size_t)src[b] * F_ + f];
    h2wT[(size_t)f * B_ + b] = f2b(v);
}

// ---- one coalesced pass over gathered city/prov rows: pack bitmask + rowcount ----
__global__ __launch_bounds__(256) void k_maskcnt(const int* __restrict__ city, const int* __restrict__ prov,
                                                 const int* __restrict__ src,
                                                 uint32_t* __restrict__ BMc, uint32_t* __restrict__ BMp,
                                                 float* __restrict__ w3, float* __restrict__ w4) {
    __shared__ int red[256];
    int b = blockIdx.x & (B_ - 1);
    bool isC = blockIdx.x < B_;
    const int* adj = isC ? city : prov;
    uint32_t* BM = isC ? BMc : BMp;
    float* wout = isC ? w3 : w4;
    const int* rowp = adj + (size_t)src[b] * N_;
    int t = threadIdx.x;
    int wv = t >> 6, ln = t & 63;
    int cnt = 0;
#pragma unroll 4
    for (int i = 0; i < N_ / 256; ++i) {                 // 32 coalesced 1KB sweeps
        int v = rowp[i * 256 + t];
        unsigned long long bal = __ballot(v > 0);
        cnt += (v > 0);
        if (ln == 0) {
            int widx = i * 8 + wv * 2;                   // n0 = i*256 + wv*64
            BM[(size_t)b * 256 + widx] = (uint32_t)bal;
            BM[(size_t)b * 256 + widx + 1] = (uint32_t)(bal >> 32);
        }
    }
    red[t] = cnt; __syncthreads();
    for (int s = 128; s > 0; s >>= 1) { if (t < s) red[t] += red[t + s]; __syncthreads(); }
    if (t == 0) wout[b] = red[0] > 0 ? 1.0f / (float)red[0] : 0.0f;
}

// ---- expand bits -> GT[n][b] bf16 = cbit*w3[b] + pbit*w4[b] (bitmasks are L2-resident) ----
__global__ __launch_bounds__(256) void k_gbuild(const uint32_t* __restrict__ BMc, const uint32_t* __restrict__ BMp,
                                                const float* __restrict__ w3, const float* __restrict__ w4,
                                                unsigned short* __restrict__ GT) {
    int n = blockIdx.x;
    int t = threadIdx.x;
    int word = n >> 5;
    uint32_t bit = 1u << (n & 31);
    int b0 = t * 8;
    vs8 o;
#pragma unroll
    for (int j = 0; j < 8; ++j) {
        int b = b0 + j;
        float v = 0.f;
        if (BMc[(size_t)b * 256 + word] & bit) v += w3[b];
        if (BMp[(size_t)b * 256 + word] & bit) v += w4[b];
        o[j] = (short)f2b(v);
    }
    *(vs8*)(GT + (size_t)n * B_ + b0) = o;
}

// ---------------- u_in += GT @ h2wT^T  (clean bf16 GEMM, K=B) ----------------
__global__ __launch_bounds__(256) void k_gemmC2(const unsigned short* __restrict__ GT,
                                                const unsigned short* __restrict__ h2wT,
                                                float* __restrict__ u_in) {
    int w = threadIdx.x >> 6, l = threadIdx.x & 63;
    int lr = l & 15, lg = l >> 4;
    int nb = blockIdx.x * 32 + (w >> 1) * 16;
    int fb = (w & 1) * 64;
    vf4 acc[4] = {};
    const unsigned short* ap = GT + (size_t)(nb + lr) * B_ + lg * 8;
    for (int b0 = 0; b0 < B_; b0 += 32) {
        ABu af; af.s = *(const vs8*)(ap + b0);
#pragma unroll
        for (int q = 0; q < 4; ++q) {
            ABu bf; bf.s = *(const vs8*)(h2wT + (size_t)(fb + q * 16 + lr) * B_ + b0 + lg * 8);
            acc[q] = mfma16(af, bf, acc[q]);
        }
    }
#pragma unroll
    for (int q = 0; q < 4; ++q)
#pragma unroll
        for (int r = 0; r < 4; ++r) {
            int row = blockIdx.x * 32 + (w >> 1) * 16 + lg * 4 + r;
            int col = fb + q * 16 + lr;
            u_in[(size_t)row * F_ + col] += acc[q][r];   // stream-ordered after gemmA: plain add
        }
}

// ---------------- per-row of inter_adj: bitmask + softmax row stats ----------------
__global__ __launch_bounds__(256) void k_adjstats(const int* __restrict__ adj, const float* __restrict__ s1,
                                                  const float* __restrict__ s2, unsigned short* __restrict__ bm,
                                                  float* __restrict__ rowmax, float* __restrict__ rowinv) {
    __shared__ float red[256];
    int n = blockIdx.x, t = threadIdx.x;
    const int* rp = adj + (size_t)n * M_ + t * 16;
    float sv[16]; unsigned mask = 0;
#pragma unroll
    for (int c = 0; c < 4; ++c) {
        int4 v = *(const int4*)(rp + c * 4);
        if (v.x > 0) mask |= 1u << (c * 4 + 0);
        if (v.y > 0) mask |= 1u << (c * 4 + 1);
        if (v.z > 0) mask |= 1u << (c * 4 + 2);
        if (v.w > 0) mask |= 1u << (c * 4 + 3);
        float4 s = *(const float4*)(s1 + t * 16 + c * 4);
        sv[c * 4 + 0] = s.x; sv[c * 4 + 1] = s.y; sv[c * 4 + 2] = s.z; sv[c * 4 + 3] = s.w;
    }
    bm[(size_t)n * 256 + t] = (unsigned short)(mask & 0xffffu);
    float mx = -3.0e38f;
#pragma unroll
    for (int j = 0; j < 16; ++j) if (mask & (1u << j)) mx = fmaxf(mx, sv[j]);
    red[t] = mx; __syncthreads();
    for (int s = 128; s > 0; s >>= 1) { if (t < s) red[t] = fmaxf(red[t], red[t + s]); __syncthreads(); }
    float s1mx = red[0];
    __syncthreads();
    float s2n = s2[n];
    float rmx = lrelu(s2n + s1mx);
    float sum = 0.f;
#pragma unroll
    for (int j = 0; j < 16; ++j) if (mask & (1u << j)) sum += __expf(lrelu(s2n + sv[j]) - rmx);
    red[t] = sum; __syncthreads();
    for (int s = 128; s > 0; s >>= 1) { if (t < s) red[t] += red[t + s]; __syncthreads(); }
    if (t == 0) {
        bool any = s1mx > -2.9e38f;
        rowmax[n] = any ? rmx : 0.f;
        rowinv[n] = (any && red[0] > 0.f) ? 1.0f / red[0] : 0.f;
    }
}

// ---------------- materialize att bf16 [N][M] ----------------
__global__ __launch_bounds__(256) void k_attmat(const unsigned char* __restrict__ bm8,
                                                const float* __restrict__ s1, const float* __restrict__ s2,
                                                const float* __restrict__ rowmax, const float* __restrict__ rowinv,
                                                unsigned short* __restrict__ att) {
    int id = blockIdx.x * 256 + threadIdx.x;             // N*M/8 threads
    int n = id >> 9;
    int m = (id & 511) * 8;
    unsigned bits = bm8[(size_t)n * 512 + (m >> 3)];
    float s2n = s2[n], rmx = rowmax[n], rin = rowinv[n];
    float4 sa = *(const float4*)(s1 + m);
    float4 sb = *(const float4*)(s1 + m + 4);
    float sv[8] = {sa.x, sa.y, sa.z, sa.w, sb.x, sb.y, sb.z, sb.w};
    vs8 o;
#pragma unroll
    for (int j = 0; j < 8; ++j) {
        float v = (bits & (1u << j)) ? __expf(lrelu(s2n + sv[j]) - rmx) * rin : 0.f;
        o[j] = (short)f2b(v);
    }
    *(vs8*)(att + (size_t)n * M_ + m) = o;
}

// ---------------- u_in += att @ h1  (B from h1T) ----------------
__global__ __launch_bounds__(256) void k_gemmA(const unsigned short* __restrict__ att,
                                               const unsigned short* __restrict__ h1T,
                                               float* __restrict__ u_in) {
    int w = threadIdx.x >> 6, l = threadIdx.x & 63;
    int lr = l & 15, lg = l >> 4;
    int nb = blockIdx.x * 32 + (w >> 1) * 16;
    int fb = (w & 1) * 64;
    vf4 acc[4] = {};
    const unsigned short* ap = att + (size_t)(nb + lr) * M_ + lg * 8;
    int m0s = blockIdx.y * 2048;
    for (int m0 = m0s; m0 < m0s + 2048; m0 += 32) {
        ABu af; af.s = *(const vs8*)(ap + m0);
#pragma unroll
        for (int q = 0; q < 4; ++q) {
            ABu bf; bf.s = *(const vs8*)(h1T + (size_t)(fb + q * 16 + lr) * M_ + m0 + lg * 8);
            acc[q] = mfma16(af, bf, acc[q]);
        }
    }
#pragma unroll
    for (int q = 0; q < 4; ++q)
#pragma unroll
        for (int r = 0; r < 4; ++r)
            atomicAdd(&u_in[(size_t)(blockIdx.x * 32 + (w >> 1) * 16 + lg * 4 + r) * F_ + fb + q * 16 + lr],
                      acc[q][r]);
}

// ---------------- v_in += att.T @ h2  (B from h2T) ----------------
__global__ __launch_bounds__(256) void k_gemmB(const unsigned short* __restrict__ att,
                                               const unsigned short* __restrict__ h2T,
                                               float* __restrict__ v_in) {
    int w = threadIdx.x >> 6, l = threadIdx.x & 63;
    int lr = l & 15, lg = l >> 4;
    int mb = blockIdx.x * 16;
    int fb = w * 32;
    vf4 acc[2] = {};
    int n0s = blockIdx.y * 2048;
    for (int n0 = n0s; n0 < n0s + 2048; n0 += 32) {
        ABu af;
#pragma unroll
        for (int j = 0; j < 8; ++j)
            af.s[j] = (short)att[(size_t)(n0 + lg * 8 + j) * M_ + mb + lr];
#pragma unroll
        for (int q = 0; q < 2; ++q) {
            ABu bf; bf.s = *(const vs8*)(h2T + (size_t)(fb + q * 16 + lr) * N_ + n0 + lg * 8);
            acc[q] = mfma16(af, bf, acc[q]);
        }
    }
#pragma unroll
    for (int q = 0; q < 2; ++q)
#pragma unroll
        for (int r = 0; r < 4; ++r)
            atomicAdd(&v_in[(size_t)(mb + lg * 4 + r) * F_ + fb + q * 16 + lr], acc[q][r]);
}

// ---------------- batchnorm column stats (sum, sumsq) ----------------
__global__ __launch_bounds__(256) void k_bnstats(const float* __restrict__ P, int R,
                                                 float* __restrict__ sum, float* __restrict__ sq) {
    __shared__ float r1[256], r2[256];
    int f = threadIdx.x & 127;
    int half = threadIdx.x >> 7;
    float s = 0.f, s2v = 0.f;
    for (int r = blockIdx.x * 2 + half; r < R; r += gridDim.x * 2) {
        float v = P[(size_t)r * F_ + f];
        s += v; s2v += v * v;
    }
    r1[threadIdx.x] = s; r2[threadIdx.x] = s2v;
    __syncthreads();
    if (half == 0) {
        atomicAdd(&sum[f], r1[f] + r1[f + 128]);
        atomicAdd(&sq[f], r2[f] + r2[f + 128]);
    }
}

// ---------------- scale/shift from stats ----------------
__global__ void k_bnfinal(const float* __restrict__ stats, const float* __restrict__ g1,
                          const float* __restrict__ b1, const float* __restrict__ g2,
                          const float* __restrict__ b2, float* __restrict__ scsh) {
    int t = threadIdx.x;                                  // 256
    int f = t & 127;
    const float* sum; const float* sq; const float* g; const float* be; float R; float* sc; float* sh;
    if (t < 128) { sum = stats;       sq = stats + 128; g = g1; be = b1; R = 4096.f; sc = scsh;       sh = scsh + 128; }
    else         { sum = stats + 256; sq = stats + 384; g = g2; be = b2; R = 8192.f; sc = scsh + 256; sh = scsh + 384; }
    float mean = sum[f] / R;
    float var = sq[f] / R - mean * mean;
    float s = g[f] * rsqrtf(var + 1e-5f);
    sc[f] = s; sh[f] = be[f] - mean * s;
}

// ---------------- apply bn + leaky + cast bf16 ----------------
__global__ void k_bnapply(const float* __restrict__ P, const float* __restrict__ scsh, int which,
                          unsigned short* __restrict__ Q) {
    int id = blockIdx.x * 256 + threadIdx.x;
    int f = id & 127;
    float s = scsh[which * 256 + f], sh = scsh[which * 256 + 128 + f];
    Q[id] = f2b(lrelu(P[id] * s + sh));
}

// ---------------- out = elu(U @ V^T) ----------------
__global__ __launch_bounds__(256) void k_gemmD(const unsigned short* __restrict__ U,
                                               const unsigned short* __restrict__ V,
                                               float* __restrict__ out) {
    int w = threadIdx.x >> 6, l = threadIdx.x & 63;
    int lr = l & 15, lg = l >> 4;
    int nb = blockIdx.x * 64 + w * 16;
    int mb = blockIdx.y * 64;
    vf4 acc[4] = {};
#pragma unroll
    for (int k0 = 0; k0 < F_; k0 += 32) {
        ABu af; af.s = *(const vs8*)(U + (size_t)(nb + lr) * F_ + k0 + lg * 8);
#pragma unroll
        for (int q = 0; q < 4; ++q) {
            ABu bf; bf.s = *(const vs8*)(V + (size_t)(mb + q * 16 + lr) * F_ + k0 + lg * 8);
            acc[q] = mfma16(af, bf, acc[q]);
        }
    }
#pragma unroll
    for (int q = 0; q < 4; ++q)
#pragma unroll
        for (int r = 0; r < 4; ++r) {
            int row = nb + lg * 4 + r;
            int col = mb + q * 16 + lr;
            float x = acc[q][r];
            out[(size_t)row * M_ + col] = x > 0.f ? x : __expf(x) - 1.f;
        }
}

extern "C" void kernel_launch(void* const* d_in, const int* in_sizes, int n_in,
                              void* d_out, int out_size, void* d_ws, size_t ws_size,
                              hipStream_t stream) {
    const float* Sinput = (const float*)d_in[0];
    const float* Rinput = (const float*)d_in[1];
    const int* inter_adj = (const int*)d_in[2];
    const int* city_adj = (const int*)d_in[3];
    const int* prov_adj = (const int*)d_in[4];
    const int* src = (const int*)d_in[5];
    const float* W1 = (const float*)d_in[6];
    const float* W2 = (const float*)d_in[7];
    const float* a = (const float*)d_in[8];
    const float* g1 = (const float*)d_in[11];
    const float* b1 = (const float*)d_in[12];
    const float* g2 = (const float*)d_in[13];
    const float* b2 = (const float*)d_in[14];
    float* out = (float*)d_out;

    char* ws = (char*)d_ws;
    size_t o = 0;
    auto take = [&](size_t bytes) { char* p = ws + o; o += (bytes + 255) & ~(size_t)255; return p; };
    float* u_in = (float*)take((size_t)N_ * F_ * 4);
    float* v_in = (float*)take((size_t)M_ * F_ * 4);
    float* stats = (float*)take(512 * 4);
    size_t zero_bytes = o;                               // u_in + v_in + stats zeroed each launch
    float* h1 = (float*)take((size_t)M_ * F_ * 4);
    float* h2 = (float*)take((size_t)N_ * F_ * 4);
    unsigned short* h1T = (unsigned short*)take((size_t)F_ * M_ * 2);
    unsigned short* h2T = (unsigned short*)take((size_t)F_ * N_ * 2);
    unsigned short* W1T = (unsigned short*)take((size_t)F_ * FIN_ * 2);
    unsigned short* W2T = (unsigned short*)take((size_t)F_ * FIN_ * 2);
    float* s1 = (float*)take(M_ * 4);
    float* s2 = (float*)take(N_ * 4);
    float* rowmax = (float*)take(N_ * 4);
    float* rowinv = (float*)take(N_ * 4);
    float* w3 = (float*)take(B_ * 4);
    float* w4 = (float*)take(B_ * 4);
    unsigned short* h2wT = (unsigned short*)take((size_t)F_ * B_ * 2);
    float* scsh = (float*)take(512 * 4);
    unsigned short* u_outb = (unsigned short*)take((size_t)N_ * F_ * 2);
    unsigned short* v_outb = (unsigned short*)take((size_t)M_ * F_ * 2);
    uint32_t* BMc = (uint32_t*)take((size_t)B_ * 256 * 4);
    uint32_t* BMp = (uint32_t*)take((size_t)B_ * 256 * 4);
    unsigned short* bm = (unsigned short*)take((size_t)N_ * 256 * 2);
    unsigned short* att = (unsigned short*)take((size_t)N_ * M_ * 2);
    unsigned short* GT = att;                            // GT[N][B] aliases att (att dead by then)
    (void)ws_size; (void)in_sizes; (void)n_in; (void)out_size;

    hipMemsetAsync(d_ws, 0, zero_bytes, stream);

    k_wprep<<<256, 256, 0, stream>>>(W1, W2, W1T, W2T);
    k_hgemm<<<M_ / 32, 256, 0, stream>>>(Rinput, W1T, h1);
    k_hgemm<<<N_ / 32, 256, 0, stream>>>(Sinput, W2T, h2);
    k_castT<<<dim3(M_ / 32, 4), 256, 0, stream>>>(h1, h1T, M_);
    k_castT<<<dim3(N_ / 32, 4), 256, 0, stream>>>(h2, h2T, N_);
    k_svec<<<(M_ + N_) / 4, 256, 0, stream>>>(h1, h2, a, s1, s2);
    k_gather<<<B_, 128, 0, stream>>>(h2, src, h2wT);
    k_maskcnt<<<2 * B_, 256, 0, stream>>>(city_adj, prov_adj, src, BMc, BMp, w3, w4);
    k_adjstats<<<N_, 256, 0, stream>>>(inter_adj, s1, s2, bm, rowmax, rowinv);
    k_attmat<<<(size_t)N_ * M_ / 8 / 256, 256, 0, stream>>>((const unsigned char*)bm, s1, s2, rowmax, rowinv, att);
    k_gemmA<<<dim3(N_ / 32, 2), 256, 0, stream>>>(att, h1T, u_in);
    k_gemmB<<<dim3(M_ / 16, 4), 256, 0, stream>>>(att, h2T, v_in);
    k_gbuild<<<N_, 256, 0, stream>>>(BMc, BMp, w3, w4, GT);     // att dead; GT aliases it
    k_gemmC2<<<N_ / 32, 256, 0, stream>>>(GT, h2wT, u_in);
    k_bnstats<<<128, 256, 0, stream>>>(v_in, M_, stats, stats + 128);
    k_bnstats<<<128, 256, 0, stream>>>(u_in, N_, stats + 256, stats + 384);
    k_bnfinal<<<1, 256, 0, stream>>>(stats, g1, b1, g2, b2, scsh);
    k_bnapply<<<M_ * F_ / 256, 256, 0, stream>>>(v_in, scsh, 0, v_outb);
    k_bnapply<<<N_ * F_ / 256, 256, 0, stream>>>(u_in, scsh, 1, u_outb);
    k_gemmD<<<dim3(N_ / 64, M_ / 64), 256, 0, stream>>>(u_outb, v_outb, out);
}

// Round 3
// 470.343 us; speedup vs baseline: 2.1476x; 1.3146x over previous
//
#include <hip/hip_runtime.h>
#include <stdint.h>

#define N_ 8192
#define M_ 4096
#define FIN_ 256
#define F_ 128
#define B_ 2048

typedef __attribute__((ext_vector_type(8))) short vs8;
typedef __attribute__((ext_vector_type(8))) __bf16 vb8;
typedef __attribute__((ext_vector_type(4))) float vf4;

union ABu { vs8 s; vb8 b; };

__device__ __forceinline__ vf4 mfma16(const ABu& a, const ABu& b, vf4 c) {
    return __builtin_amdgcn_mfma_f32_16x16x32_bf16(a.b, b.b, c, 0, 0, 0);
}
__device__ __forceinline__ unsigned short f2b(float x) {
    union { float f; unsigned u; } v; v.f = x;
    unsigned r = v.u + 0x7fffu + ((v.u >> 16) & 1u);
    return (unsigned short)(r >> 16);
}
__device__ __forceinline__ float lrelu(float x) { return x > 0.f ? x : 0.2f * x; }

// ---------------- small prep: W[256][128] f32 -> WT[128][256] bf16 ----------------
__global__ void k_wprep(const float* __restrict__ W1, const float* __restrict__ W2,
                        unsigned short* __restrict__ W1T, unsigned short* __restrict__ W2T) {
    int id = blockIdx.x * 256 + threadIdx.x;            // 0..65535
    const float* W = (id < 32768) ? W1 : W2;
    unsigned short* WT = (id < 32768) ? W1T : W2T;
    int o = id & 32767;
    int f = o >> 8, k = o & 255;
    WT[o] = f2b(W[k * F_ + f]);
}

// ---------------- h = X[rows][256] @ W  (via WT bf16), out f32 [rows][128] ----------------
__global__ __launch_bounds__(256) void k_hgemm(const float* __restrict__ X,
                                               const unsigned short* __restrict__ WT,
                                               float* __restrict__ H) {
    int w = threadIdx.x >> 6, l = threadIdx.x & 63;
    int lr = l & 15, lg = l >> 4;
    int rbase = blockIdx.x * 32 + (w >> 1) * 16;
    int fbase = (w & 1) * 64;
    vf4 acc[4] = {};
    const float* xp = X + (size_t)(rbase + lr) * FIN_ + lg * 8;
    for (int kk = 0; kk < FIN_; kk += 32) {
        float4 xa = *(const float4*)(xp + kk);
        float4 xb = *(const float4*)(xp + kk + 4);
        ABu af;
        af.s[0] = (short)f2b(xa.x); af.s[1] = (short)f2b(xa.y);
        af.s[2] = (short)f2b(xa.z); af.s[3] = (short)f2b(xa.w);
        af.s[4] = (short)f2b(xb.x); af.s[5] = (short)f2b(xb.y);
        af.s[6] = (short)f2b(xb.z); af.s[7] = (short)f2b(xb.w);
#pragma unroll
        for (int q = 0; q < 4; ++q) {
            int col = fbase + q * 16 + lr;
            ABu bf; bf.s = *(const vs8*)(WT + col * FIN_ + kk + lg * 8);
            acc[q] = mfma16(af, bf, acc[q]);
        }
    }
#pragma unroll
    for (int q = 0; q < 4; ++q)
#pragma unroll
        for (int r = 0; r < 4; ++r) {
            int row = blockIdx.x * 32 + (w >> 1) * 16 + lg * 4 + r;
            int col = fbase + q * 16 + lr;
            H[(size_t)row * F_ + col] = acc[q][r];
        }
}

// ---------------- h f32 [rows][128] -> hT bf16 [128][rows] ----------------
__global__ void k_castT(const float* __restrict__ Hsrc, unsigned short* __restrict__ HT, int rows) {
    __shared__ float tile[32][33];
    int r0 = blockIdx.x * 32, f0 = blockIdx.y * 32;
    int tx = threadIdx.x & 31, ty = threadIdx.x >> 5;   // 32 x 8
#pragma unroll
    for (int p = 0; p < 4; ++p)
        tile[ty + p * 8][tx] = Hsrc[(size_t)(r0 + ty + p * 8) * F_ + f0 + tx];
    __syncthreads();
#pragma unroll
    for (int p = 0; p < 4; ++p)
        HT[(size_t)(f0 + ty + p * 8) * rows + r0 + tx] = f2b(tile[tx][ty + p * 8]);
}

// ---------------- s1[m]=h1[m]·a[:128], s2[n]=h2[n]·a[128:] ----------------
__global__ void k_svec(const float* __restrict__ h1, const float* __restrict__ h2,
                       const float* __restrict__ a, float* __restrict__ s1, float* __restrict__ s2) {
    int w = threadIdx.x >> 6, l = threadIdx.x & 63;
    int row = blockIdx.x * 4 + w;                        // 0..12287
    const float* hp; const float* ap; float* sp;
    if (row < M_) { hp = h1 + (size_t)row * F_; ap = a;       sp = s1 + row; }
    else { int r = row - M_; hp = h2 + (size_t)r * F_; ap = a + F_; sp = s2 + r; }
    float v = hp[l] * ap[l] + hp[64 + l] * ap[64 + l];
    for (int off = 32; off > 0; off >>= 1) v += __shfl_down(v, off, 64);
    if (l == 0) *sp = v;
}

// ---------------- gather h2wT[f][b] = bf16(h2[src[b]][f]) ----------------
__global__ void k_gather(const float* __restrict__ h2, const int* __restrict__ src,
                         unsigned short* __restrict__ h2wT) {
    int b = blockIdx.x;                                  // 2048
    int f = threadIdx.x;                                 // 128
    float v = h2[(size_t)src[b] * F_ + f];
    h2wT[(size_t)f * B_ + b] = f2b(v);
}

// ---- one coalesced pass over gathered city/prov rows: TRANSPOSED bitmask + rowcount ----
// BMt layout: BMt[word][b] (word = n/32) so consumers sweep b contiguously.
__global__ __launch_bounds__(256) void k_maskcnt(const int* __restrict__ city, const int* __restrict__ prov,
                                                 const int* __restrict__ src,
                                                 uint32_t* __restrict__ BMtc, uint32_t* __restrict__ BMtp,
                                                 float* __restrict__ w3, float* __restrict__ w4) {
    __shared__ int red[256];
    int b = blockIdx.x & (B_ - 1);
    bool isC = blockIdx.x < B_;
    const int* adj = isC ? city : prov;
    uint32_t* BM = isC ? BMtc : BMtp;
    float* wout = isC ? w3 : w4;
    const int* rowp = adj + (size_t)src[b] * N_;
    int t = threadIdx.x;
    int wv = t >> 6, ln = t & 63;
    int cnt = 0;
#pragma unroll 4
    for (int i = 0; i < N_ / 256; ++i) {                 // 32 coalesced 1KB sweeps
        int v = rowp[i * 256 + t];
        unsigned long long bal = __ballot(v > 0);
        cnt += (v > 0);
        if (ln == 0) {
            int widx = i * 8 + wv * 2;                   // n0 = i*256 + wv*64
            BM[(size_t)widx * B_ + b] = (uint32_t)bal;
            BM[(size_t)(widx + 1) * B_ + b] = (uint32_t)(bal >> 32);
        }
    }
    red[t] = cnt; __syncthreads();
    for (int s = 128; s > 0; s >>= 1) { if (t < s) red[t] += red[t + s]; __syncthreads(); }
    if (t == 0) wout[b] = red[0] > 0 ? 1.0f / (float)red[0] : 0.0f;
}

// ---- u_in += G @ h2wT^T with G[n][b] = cbit*w3[b]+pbit*w4[b] built on the fly from BMt ----
__global__ __launch_bounds__(256) void k_gemmC3(const uint32_t* __restrict__ BMtc, const uint32_t* __restrict__ BMtp,
                                                const float* __restrict__ w3, const float* __restrict__ w4,
                                                const unsigned short* __restrict__ h2wT,
                                                float* __restrict__ u_in) {
    int w = threadIdx.x >> 6, l = threadIdx.x & 63;
    int lr = l & 15, lg = l >> 4;
    int nb = blockIdx.x * 32 + (w >> 1) * 16;
    int fb = (w & 1) * 64;
    int n = nb + lr;
    int wi = n >> 5;                                     // uniform across the 16-row tile
    int bitpos = n & 31;
    const uint32_t* bc = BMtc + (size_t)wi * B_;
    const uint32_t* bp = BMtp + (size_t)wi * B_;
    vf4 acc[4] = {};
    for (int b0 = 0; b0 < B_; b0 += 32) {
        int bb = b0 + lg * 8;
        uint4 c0 = *(const uint4*)(bc + bb);
        uint4 c1 = *(const uint4*)(bc + bb + 4);
        uint4 p0 = *(const uint4*)(bp + bb);
        uint4 p1 = *(const uint4*)(bp + bb + 4);
        float4 wa = *(const float4*)(w3 + bb);
        float4 wb = *(const float4*)(w3 + bb + 4);
        float4 wc = *(const float4*)(w4 + bb);
        float4 wd = *(const float4*)(w4 + bb + 4);
        uint32_t cw[8] = {c0.x, c0.y, c0.z, c0.w, c1.x, c1.y, c1.z, c1.w};
        uint32_t pw[8] = {p0.x, p0.y, p0.z, p0.w, p1.x, p1.y, p1.z, p1.w};
        float w3v[8] = {wa.x, wa.y, wa.z, wa.w, wb.x, wb.y, wb.z, wb.w};
        float w4v[8] = {wc.x, wc.y, wc.z, wc.w, wd.x, wd.y, wd.z, wd.w};
        ABu af;
#pragma unroll
        for (int j = 0; j < 8; ++j) {
            float v = (((cw[j] >> bitpos) & 1u) ? w3v[j] : 0.f) + (((pw[j] >> bitpos) & 1u) ? w4v[j] : 0.f);
            af.s[j] = (short)f2b(v);
        }
#pragma unroll
        for (int q = 0; q < 4; ++q) {
            ABu bf; bf.s = *(const vs8*)(h2wT + (size_t)(fb + q * 16 + lr) * B_ + b0 + lg * 8);
            acc[q] = mfma16(af, bf, acc[q]);
        }
    }
#pragma unroll
    for (int q = 0; q < 4; ++q)
#pragma unroll
        for (int r = 0; r < 4; ++r) {
            int row = nb + lg * 4 + r;
            int col = fb + q * 16 + lr;
            u_in[(size_t)row * F_ + col] += acc[q][r];   // runs after gemmA: plain add, single writer
        }
}

// ---------------- per-row of inter_adj: bitmask + softmax row stats ----------------
__global__ __launch_bounds__(256) void k_adjstats(const int* __restrict__ adj, const float* __restrict__ s1,
                                                  const float* __restrict__ s2, unsigned short* __restrict__ bm,
                                                  float* __restrict__ rowmax, float* __restrict__ rowinv) {
    __shared__ float red[256];
    int n = blockIdx.x, t = threadIdx.x;
    const int* rp = adj + (size_t)n * M_ + t * 16;
    float sv[16]; unsigned mask = 0;
#pragma unroll
    for (int c = 0; c < 4; ++c) {
        int4 v = *(const int4*)(rp + c * 4);
        if (v.x > 0) mask |= 1u << (c * 4 + 0);
        if (v.y > 0) mask |= 1u << (c * 4 + 1);
        if (v.z > 0) mask |= 1u << (c * 4 + 2);
        if (v.w > 0) mask |= 1u << (c * 4 + 3);
        float4 s = *(const float4*)(s1 + t * 16 + c * 4);
        sv[c * 4 + 0] = s.x; sv[c * 4 + 1] = s.y; sv[c * 4 + 2] = s.z; sv[c * 4 + 3] = s.w;
    }
    bm[(size_t)n * 256 + t] = (unsigned short)(mask & 0xffffu);
    float mx = -3.0e38f;
#pragma unroll
    for (int j = 0; j < 16; ++j) if (mask & (1u << j)) mx = fmaxf(mx, sv[j]);
    red[t] = mx; __syncthreads();
    for (int s = 128; s > 0; s >>= 1) { if (t < s) red[t] = fmaxf(red[t], red[t + s]); __syncthreads(); }
    float s1mx = red[0];
    __syncthreads();
    float s2n = s2[n];
    float rmx = lrelu(s2n + s1mx);
    float sum = 0.f;
#pragma unroll
    for (int j = 0; j < 16; ++j) if (mask & (1u << j)) sum += __expf(lrelu(s2n + sv[j]) - rmx);
    red[t] = sum; __syncthreads();
    for (int s = 128; s > 0; s >>= 1) { if (t < s) red[t] += red[t + s]; __syncthreads(); }
    if (t == 0) {
        bool any = s1mx > -2.9e38f;
        rowmax[n] = any ? rmx : 0.f;
        rowinv[n] = (any && red[0] > 0.f) ? 1.0f / red[0] : 0.f;
    }
}

// ---------------- materialize att bf16 [N][M] ----------------
__global__ __launch_bounds__(256) void k_attmat(const unsigned char* __restrict__ bm8,
                                                const float* __restrict__ s1, const float* __restrict__ s2,
                                                const float* __restrict__ rowmax, const float* __restrict__ rowinv,
                                                unsigned short* __restrict__ att) {
    int id = blockIdx.x * 256 + threadIdx.x;             // N*M/8 threads
    int n = id >> 9;
    int m = (id & 511) * 8;
    unsigned bits = bm8[(size_t)n * 512 + (m >> 3)];
    float s2n = s2[n], rmx = rowmax[n], rin = rowinv[n];
    float4 sa = *(const float4*)(s1 + m);
    float4 sb = *(const float4*)(s1 + m + 4);
    float sv[8] = {sa.x, sa.y, sa.z, sa.w, sb.x, sb.y, sb.z, sb.w};
    vs8 o;
#pragma unroll
    for (int j = 0; j < 8; ++j) {
        float v = (bits & (1u << j)) ? __expf(lrelu(s2n + sv[j]) - rmx) * rin : 0.f;
        o[j] = (short)f2b(v);
    }
    *(vs8*)(att + (size_t)n * M_ + m) = o;
}

// ---------------- u_in += att @ h1  (B from h1T) ----------------
__global__ __launch_bounds__(256) void k_gemmA(const unsigned short* __restrict__ att,
                                               const unsigned short* __restrict__ h1T,
                                               float* __restrict__ u_in) {
    int w = threadIdx.x >> 6, l = threadIdx.x & 63;
    int lr = l & 15, lg = l >> 4;
    int nb = blockIdx.x * 32 + (w >> 1) * 16;
    int fb = (w & 1) * 64;
    vf4 acc[4] = {};
    const unsigned short* ap = att + (size_t)(nb + lr) * M_ + lg * 8;
    int m0s = blockIdx.y * 2048;
    for (int m0 = m0s; m0 < m0s + 2048; m0 += 32) {
        ABu af; af.s = *(const vs8*)(ap + m0);
#pragma unroll
        for (int q = 0; q < 4; ++q) {
            ABu bf; bf.s = *(const vs8*)(h1T + (size_t)(fb + q * 16 + lr) * M_ + m0 + lg * 8);
            acc[q] = mfma16(af, bf, acc[q]);
        }
    }
#pragma unroll
    for (int q = 0; q < 4; ++q)
#pragma unroll
        for (int r = 0; r < 4; ++r)
            atomicAdd(&u_in[(size_t)(blockIdx.x * 32 + (w >> 1) * 16 + lg * 4 + r) * F_ + fb + q * 16 + lr],
                      acc[q][r]);
}

// ---- v_in += att.T @ h2: LDS-transposed att tiles, coalesced global reads ----
__global__ __launch_bounds__(256) void k_gemmB(const unsigned short* __restrict__ att,
                                               const unsigned short* __restrict__ h2T,
                                               float* __restrict__ v_in) {
    __shared__ unsigned short lds[32][34];               // [m_local][n_local], stride 34 spreads banks
    int t = threadIdx.x;
    int w = t >> 6, l = t & 63;
    int lr = l & 15, lg = l >> 4;
    int mb = blockIdx.x * 32;
    int mh = (w >> 1) * 16;                              // wave's m-half
    int fb = (w & 1) * 64;                               // wave's f-half
    int si = t >> 3;                                     // stage: n_local 0..31
    int sc = (t & 7) * 4;                                // stage: m_local quad 0..28
    vf4 acc[4] = {};
    int n0s = blockIdx.y * (N_ / 4);
    for (int n0 = n0s; n0 < n0s + N_ / 4; n0 += 32) {
        uint2 dv = *(const uint2*)(att + (size_t)(n0 + si) * M_ + mb + sc);  // 4 u16, coalesced 8B
        __syncthreads();                                  // prev iteration's reads done
        lds[sc + 0][si] = (unsigned short)(dv.x & 0xffffu);
        lds[sc + 1][si] = (unsigned short)(dv.x >> 16);
        lds[sc + 2][si] = (unsigned short)(dv.y & 0xffffu);
        lds[sc + 3][si] = (unsigned short)(dv.y >> 16);
        __syncthreads();
        ABu af; af.s = *(const vs8*)&lds[mh + lr][lg * 8];
#pragma unroll
        for (int q = 0; q < 4; ++q) {
            ABu bf; bf.s = *(const vs8*)(h2T + (size_t)(fb + q * 16 + lr) * N_ + n0 + lg * 8);
            acc[q] = mfma16(af, bf, acc[q]);
        }
    }
#pragma unroll
    for (int q = 0; q < 4; ++q)
#pragma unroll
        for (int r = 0; r < 4; ++r)
            atomicAdd(&v_in[(size_t)(mb + mh + lg * 4 + r) * F_ + fb + q * 16 + lr], acc[q][r]);
}

// ---------------- batchnorm column stats (sum, sumsq) ----------------
__global__ __launch_bounds__(256) void k_bnstats(const float* __restrict__ P, int R,
                                                 float* __restrict__ sum, float* __restrict__ sq) {
    __shared__ float r1[256], r2[256];
    int f = threadIdx.x & 127;
    int half = threadIdx.x >> 7;
    float s = 0.f, s2v = 0.f;
    for (int r = blockIdx.x * 2 + half; r < R; r += gridDim.x * 2) {
        float v = P[(size_t)r * F_ + f];
        s += v; s2v += v * v;
    }
    r1[threadIdx.x] = s; r2[threadIdx.x] = s2v;
    __syncthreads();
    if (half == 0) {
        atomicAdd(&sum[f], r1[f] + r1[f + 128]);
        atomicAdd(&sq[f], r2[f] + r2[f + 128]);
    }
}

// ---------------- scale/shift from stats ----------------
__global__ void k_bnfinal(const float* __restrict__ stats, const float* __restrict__ g1,
                          const float* __restrict__ b1, const float* __restrict__ g2,
                          const float* __restrict__ b2, float* __restrict__ scsh) {
    int t = threadIdx.x;                                  // 256
    int f = t & 127;
    const float* sum; const float* sq; const float* g; const float* be; float R; float* sc; float* sh;
    if (t < 128) { sum = stats;       sq = stats + 128; g = g1; be = b1; R = 4096.f; sc = scsh;       sh = scsh + 128; }
    else         { sum = stats + 256; sq = stats + 384; g = g2; be = b2; R = 8192.f; sc = scsh + 256; sh = scsh + 384; }
    float mean = sum[f] / R;
    float var = sq[f] / R - mean * mean;
    float s = g[f] * rsqrtf(var + 1e-5f);
    sc[f] = s; sh[f] = be[f] - mean * s;
}

// ---------------- apply bn + leaky + cast bf16 ----------------
__global__ void k_bnapply(const float* __restrict__ P, const float* __restrict__ scsh, int which,
                          unsigned short* __restrict__ Q) {
    int id = blockIdx.x * 256 + threadIdx.x;
    int f = id & 127;
    float s = scsh[which * 256 + f], sh = scsh[which * 256 + 128 + f];
    Q[id] = f2b(lrelu(P[id] * s + sh));
}

// ---------------- out = elu(U @ V^T) ----------------
__global__ __launch_bounds__(256) void k_gemmD(const unsigned short* __restrict__ U,
                                               const unsigned short* __restrict__ V,
                                               float* __restrict__ out) {
    int w = threadIdx.x >> 6, l = threadIdx.x & 63;
    int lr = l & 15, lg = l >> 4;
    int nb = blockIdx.x * 64 + w * 16;
    int mb = blockIdx.y * 64;
    vf4 acc[4] = {};
#pragma unroll
    for (int k0 = 0; k0 < F_; k0 += 32) {
        ABu af; af.s = *(const vs8*)(U + (size_t)(nb + lr) * F_ + k0 + lg * 8);
#pragma unroll
        for (int q = 0; q < 4; ++q) {
            ABu bf; bf.s = *(const vs8*)(V + (size_t)(mb + q * 16 + lr) * F_ + k0 + lg * 8);
            acc[q] = mfma16(af, bf, acc[q]);
        }
    }
#pragma unroll
    for (int q = 0; q < 4; ++q)
#pragma unroll
        for (int r = 0; r < 4; ++r) {
            int row = nb + lg * 4 + r;
            int col = mb + q * 16 + lr;
            float x = acc[q][r];
            out[(size_t)row * M_ + col] = x > 0.f ? x : __expf(x) - 1.f;
        }
}

extern "C" void kernel_launch(void* const* d_in, const int* in_sizes, int n_in,
                              void* d_out, int out_size, void* d_ws, size_t ws_size,
                              hipStream_t stream) {
    const float* Sinput = (const float*)d_in[0];
    const float* Rinput = (const float*)d_in[1];
    const int* inter_adj = (const int*)d_in[2];
    const int* city_adj = (const int*)d_in[3];
    const int* prov_adj = (const int*)d_in[4];
    const int* src = (const int*)d_in[5];
    const float* W1 = (const float*)d_in[6];
    const float* W2 = (const float*)d_in[7];
    const float* a = (const float*)d_in[8];
    const float* g1 = (const float*)d_in[11];
    const float* b1 = (const float*)d_in[12];
    const float* g2 = (const float*)d_in[13];
    const float* b2 = (const float*)d_in[14];
    float* out = (float*)d_out;

    char* ws = (char*)d_ws;
    size_t o = 0;
    auto take = [&](size_t bytes) { char* p = ws + o; o += (bytes + 255) & ~(size_t)255; return p; };
    float* u_in = (float*)take((size_t)N_ * F_ * 4);
    float* v_in = (float*)take((size_t)M_ * F_ * 4);
    float* stats = (float*)take(512 * 4);
    size_t zero_bytes = o;                               // u_in + v_in + stats zeroed each launch
    float* h1 = (float*)take((size_t)M_ * F_ * 4);
    float* h2 = (float*)take((size_t)N_ * F_ * 4);
    unsigned short* h1T = (unsigned short*)take((size_t)F_ * M_ * 2);
    unsigned short* h2T = (unsigned short*)take((size_t)F_ * N_ * 2);
    unsigned short* W1T = (unsigned short*)take((size_t)F_ * FIN_ * 2);
    unsigned short* W2T = (unsigned short*)take((size_t)F_ * FIN_ * 2);
    float* s1 = (float*)take(M_ * 4);
    float* s2 = (float*)take(N_ * 4);
    float* rowmax = (float*)take(N_ * 4);
    float* rowinv = (float*)take(N_ * 4);
    float* w3 = (float*)take(B_ * 4);
    float* w4 = (float*)take(B_ * 4);
    unsigned short* h2wT = (unsigned short*)take((size_t)F_ * B_ * 2);
    float* scsh = (float*)take(512 * 4);
    unsigned short* u_outb = (unsigned short*)take((size_t)N_ * F_ * 2);
    unsigned short* v_outb = (unsigned short*)take((size_t)M_ * F_ * 2);
    uint32_t* BMtc = (uint32_t*)take((size_t)256 * B_ * 4);
    uint32_t* BMtp = (uint32_t*)take((size_t)256 * B_ * 4);
    unsigned short* bm = (unsigned short*)take((size_t)N_ * 256 * 2);
    unsigned short* att = (unsigned short*)take((size_t)N_ * M_ * 2);
    (void)ws_size; (void)in_sizes; (void)n_in; (void)out_size;

    hipMemsetAsync(d_ws, 0, zero_bytes, stream);

    k_wprep<<<256, 256, 0, stream>>>(W1, W2, W1T, W2T);
    k_hgemm<<<M_ / 32, 256, 0, stream>>>(Rinput, W1T, h1);
    k_hgemm<<<N_ / 32, 256, 0, stream>>>(Sinput, W2T, h2);
    k_castT<<<dim3(M_ / 32, 4), 256, 0, stream>>>(h1, h1T, M_);
    k_castT<<<dim3(N_ / 32, 4), 256, 0, stream>>>(h2, h2T, N_);
    k_svec<<<(M_ + N_) / 4, 256, 0, stream>>>(h1, h2, a, s1, s2);
    k_gather<<<B_, 128, 0, stream>>>(h2, src, h2wT);
    k_maskcnt<<<2 * B_, 256, 0, stream>>>(city_adj, prov_adj, src, BMtc, BMtp, w3, w4);
    k_adjstats<<<N_, 256, 0, stream>>>(inter_adj, s1, s2, bm, rowmax, rowinv);
    k_attmat<<<(size_t)N_ * M_ / 8 / 256, 256, 0, stream>>>((const unsigned char*)bm, s1, s2, rowmax, rowinv, att);
    k_gemmA<<<dim3(N_ / 32, 2), 256, 0, stream>>>(att, h1T, u_in);
    k_gemmB<<<dim3(M_ / 32, 4), 256, 0, stream>>>(att, h2T, v_in);
    k_gemmC3<<<N_ / 32, 256, 0, stream>>>(BMtc, BMtp, w3, w4, h2wT, u_in);
    k_bnstats<<<128, 256, 0, stream>>>(v_in, M_, stats, stats + 128);
    k_bnstats<<<128, 256, 0, stream>>>(u_in, N_, stats + 256, stats + 384);
    k_bnfinal<<<1, 256, 0, stream>>>(stats, g1, b1, g2, b2, scsh);
    k_bnapply<<<M_ * F_ / 256, 256, 0, stream>>>(v_in, scsh, 0, v_outb);
    k_bnapply<<<N_ * F_ / 256, 256, 0, stream>>>(u_in, scsh, 1, u_outb);
    k_gemmD<<<dim3(N_ / 64, M_ / 64), 256, 0, stream>>>(u_outb, v_outb, out);
}

// Round 4
// 453.345 us; speedup vs baseline: 2.2282x; 1.0375x over previous
//
#include <hip/hip_runtime.h>
#include <stdint.h>

#define N_ 8192
#define M_ 4096
#define FIN_ 256
#define F_ 128
#define B_ 2048

typedef __attribute__((ext_vector_type(8))) short vs8;
typedef __attribute__((ext_vector_type(8))) __bf16 vb8;
typedef __attribute__((ext_vector_type(4))) float vf4;

union ABu { vs8 s; vb8 b; };

__device__ __forceinline__ vf4 mfma16(const ABu& a, const ABu& b, vf4 c) {
    return __builtin_amdgcn_mfma_f32_16x16x32_bf16(a.b, b.b, c, 0, 0, 0);
}
__device__ __forceinline__ unsigned short f2b(float x) {
    union { float f; unsigned u; } v; v.f = x;
    unsigned r = v.u + 0x7fffu + ((v.u >> 16) & 1u);
    return (unsigned short)(r >> 16);
}
__device__ __forceinline__ float lrelu(float x) { return x > 0.f ? x : 0.2f * x; }

// ---------------- small prep: W[256][128] f32 -> WT[128][256] bf16 ----------------
__global__ void k_wprep(const float* __restrict__ W1, const float* __restrict__ W2,
                        unsigned short* __restrict__ W1T, unsigned short* __restrict__ W2T) {
    int id = blockIdx.x * 256 + threadIdx.x;            // 0..65535
    const float* W = (id < 32768) ? W1 : W2;
    unsigned short* WT = (id < 32768) ? W1T : W2T;
    int o = id & 32767;
    int f = o >> 8, k = o & 255;
    WT[o] = f2b(W[k * F_ + f]);
}

// ---- h1 = Rinput@W1, h2 = Sinput@W2 in ONE launch; 16 rows/block, 4 waves x 32f ----
__global__ __launch_bounds__(256) void k_hgemm2(const float* __restrict__ Rin, const float* __restrict__ Sin,
                                                const unsigned short* __restrict__ W1T,
                                                const unsigned short* __restrict__ W2T,
                                                float* __restrict__ h1, float* __restrict__ h2) {
    int w = threadIdx.x >> 6, l = threadIdx.x & 63;
    int lr = l & 15, lg = l >> 4;
    int gr = blockIdx.x * 16;
    const float* X; float* H; const unsigned short* WT; int row0;
    if (gr < M_) { X = Rin; H = h1; WT = W1T; row0 = gr; }
    else         { X = Sin; H = h2; WT = W2T; row0 = gr - M_; }
    int fbase = w * 32;
    vf4 acc[2] = {};
    const float* xp = X + (size_t)(row0 + lr) * FIN_ + lg * 8;
#pragma unroll
    for (int kk = 0; kk < FIN_; kk += 32) {
        float4 xa = *(const float4*)(xp + kk);
        float4 xb = *(const float4*)(xp + kk + 4);
        ABu af;
        af.s[0] = (short)f2b(xa.x); af.s[1] = (short)f2b(xa.y);
        af.s[2] = (short)f2b(xa.z); af.s[3] = (short)f2b(xa.w);
        af.s[4] = (short)f2b(xb.x); af.s[5] = (short)f2b(xb.y);
        af.s[6] = (short)f2b(xb.z); af.s[7] = (short)f2b(xb.w);
#pragma unroll
        for (int q = 0; q < 2; ++q) {
            ABu bf; bf.s = *(const vs8*)(WT + (fbase + q * 16 + lr) * FIN_ + kk + lg * 8);
            acc[q] = mfma16(af, bf, acc[q]);
        }
    }
#pragma unroll
    for (int q = 0; q < 2; ++q)
#pragma unroll
        for (int r = 0; r < 4; ++r)
            H[(size_t)(row0 + lg * 4 + r) * F_ + fbase + q * 16 + lr] = acc[q][r];
}

// ---------------- h f32 [rows][128] -> hT bf16 [128][rows], both in one launch ----------------
__global__ void k_castT2(const float* __restrict__ h1, const float* __restrict__ h2,
                         unsigned short* __restrict__ h1T, unsigned short* __restrict__ h2T) {
    __shared__ float tile[32][33];
    int bx = blockIdx.x;
    const float* Hs; unsigned short* HT; int rows, r0;
    if (bx < M_ / 32) { Hs = h1; HT = h1T; rows = M_; r0 = bx * 32; }
    else              { Hs = h2; HT = h2T; rows = N_; r0 = (bx - M_ / 32) * 32; }
    int f0 = blockIdx.y * 32;
    int tx = threadIdx.x & 31, ty = threadIdx.x >> 5;   // 32 x 8
#pragma unroll
    for (int p = 0; p < 4; ++p)
        tile[ty + p * 8][tx] = Hs[(size_t)(r0 + ty + p * 8) * F_ + f0 + tx];
    __syncthreads();
#pragma unroll
    for (int p = 0; p < 4; ++p)
        HT[(size_t)(f0 + ty + p * 8) * rows + r0 + tx] = f2b(tile[tx][ty + p * 8]);
}

// ---- s1/s2 dot products + h2wT gather in one launch ----
__global__ void k_svecgather(const float* __restrict__ h1, const float* __restrict__ h2,
                             const float* __restrict__ a, const int* __restrict__ src,
                             float* __restrict__ s1, float* __restrict__ s2,
                             unsigned short* __restrict__ h2wT) {
    if (blockIdx.x < (M_ + N_) / 4) {
        int w = threadIdx.x >> 6, l = threadIdx.x & 63;
        int row = blockIdx.x * 4 + w;
        const float* hp; const float* ap; float* sp;
        if (row < M_) { hp = h1 + (size_t)row * F_; ap = a;       sp = s1 + row; }
        else { int r = row - M_; hp = h2 + (size_t)r * F_; ap = a + F_; sp = s2 + r; }
        float v = hp[l] * ap[l] + hp[64 + l] * ap[64 + l];
        for (int off = 32; off > 0; off >>= 1) v += __shfl_down(v, off, 64);
        if (l == 0) *sp = v;
    } else {
        int gb = blockIdx.x - (M_ + N_) / 4;
        int b = gb * 2 + (threadIdx.x >> 7);
        int f = threadIdx.x & 127;
        float v = h2[(size_t)src[b] * F_ + f];
        h2wT[(size_t)f * B_ + b] = f2b(v);
    }
}

// ---- fused: inter_adj row stats (blocks 0..N-1) + city/prov bitmask+counts (next 4096) ----
__global__ __launch_bounds__(256) void k_adjmask(const int* __restrict__ inter, const float* __restrict__ s1,
                                                 const float* __restrict__ s2, unsigned short* __restrict__ bm,
                                                 float* __restrict__ rowmax, float* __restrict__ rowinv,
                                                 const int* __restrict__ city, const int* __restrict__ prov,
                                                 const int* __restrict__ src,
                                                 uint32_t* __restrict__ BMtc, uint32_t* __restrict__ BMtp,
                                                 float* __restrict__ w3, float* __restrict__ w4) {
    __shared__ float wred[8];
    int t = threadIdx.x;
    int wv = t >> 6, ln = t & 63;
    if (blockIdx.x < N_) {
        // ---- adjstats ----
        int n = blockIdx.x;
        const int* rp = inter + (size_t)n * M_ + t * 16;
        float sv[16]; unsigned mask = 0;
#pragma unroll
        for (int c = 0; c < 4; ++c) {
            int4 v = *(const int4*)(rp + c * 4);
            if (v.x > 0) mask |= 1u << (c * 4 + 0);
            if (v.y > 0) mask |= 1u << (c * 4 + 1);
            if (v.z > 0) mask |= 1u << (c * 4 + 2);
            if (v.w > 0) mask |= 1u << (c * 4 + 3);
            float4 s = *(const float4*)(s1 + t * 16 + c * 4);
            sv[c * 4 + 0] = s.x; sv[c * 4 + 1] = s.y; sv[c * 4 + 2] = s.z; sv[c * 4 + 3] = s.w;
        }
        bm[(size_t)n * 256 + t] = (unsigned short)(mask & 0xffffu);
        float mx = -3.0e38f;
#pragma unroll
        for (int j = 0; j < 16; ++j) if (mask & (1u << j)) mx = fmaxf(mx, sv[j]);
        for (int off = 32; off > 0; off >>= 1) mx = fmaxf(mx, __shfl_down(mx, off, 64));
        if (ln == 0) wred[wv] = mx;
        __syncthreads();
        float s1mx = fmaxf(fmaxf(wred[0], wred[1]), fmaxf(wred[2], wred[3]));
        float s2n = s2[n];
        float rmx = lrelu(s2n + s1mx);
        float sum = 0.f;
#pragma unroll
        for (int j = 0; j < 16; ++j) if (mask & (1u << j)) sum += __expf(lrelu(s2n + sv[j]) - rmx);
        for (int off = 32; off > 0; off >>= 1) sum += __shfl_down(sum, off, 64);
        if (ln == 0) wred[4 + wv] = sum;
        __syncthreads();
        if (t == 0) {
            float tot = wred[4] + wred[5] + wred[6] + wred[7];
            bool any = s1mx > -2.9e38f;
            rowmax[n] = any ? rmx : 0.f;
            rowinv[n] = (any && tot > 0.f) ? 1.0f / tot : 0.f;
        }
    } else {
        // ---- maskcnt (transposed bitmask) ----
        int bb = blockIdx.x - N_;
        int b = bb & (B_ - 1);
        bool isC = bb < B_;
        const int* adj = isC ? city : prov;
        uint32_t* BM = isC ? BMtc : BMtp;
        float* wout = isC ? w3 : w4;
        const int* rowp = adj + (size_t)src[b] * N_;
        int cnt = 0;
#pragma unroll 4
        for (int i = 0; i < N_ / 256; ++i) {
            int v = rowp[i * 256 + t];
            unsigned long long bal = __ballot(v > 0);
            cnt += (v > 0);
            if (ln == 0) {
                int widx = i * 8 + wv * 2;
                BM[(size_t)widx * B_ + b] = (uint32_t)bal;
                BM[(size_t)(widx + 1) * B_ + b] = (uint32_t)(bal >> 32);
            }
        }
        float fc = (float)cnt;
        for (int off = 32; off > 0; off >>= 1) fc += __shfl_down(fc, off, 64);
        if (ln == 0) wred[wv] = fc;
        __syncthreads();
        if (t == 0) {
            float tot = wred[0] + wred[1] + wred[2] + wred[3];
            wout[b] = tot > 0.f ? 1.0f / tot : 0.f;
        }
    }
}

// ---------------- materialize att bf16 [N][M] ----------------
__global__ __launch_bounds__(256) void k_attmat(const unsigned char* __restrict__ bm8,
                                                const float* __restrict__ s1, const float* __restrict__ s2,
                                                const float* __restrict__ rowmax, const float* __restrict__ rowinv,
                                                unsigned short* __restrict__ att) {
    int id = blockIdx.x * 256 + threadIdx.x;             // N*M/8 threads
    int n = id >> 9;
    int m = (id & 511) * 8;
    unsigned bits = bm8[(size_t)n * 512 + (m >> 3)];
    float s2n = s2[n], rmx = rowmax[n], rin = rowinv[n];
    float4 sa = *(const float4*)(s1 + m);
    float4 sb = *(const float4*)(s1 + m + 4);
    float sv[8] = {sa.x, sa.y, sa.z, sa.w, sb.x, sb.y, sb.z, sb.w};
    vs8 o;
#pragma unroll
    for (int j = 0; j < 8; ++j) {
        float v = (bits & (1u << j)) ? __expf(lrelu(s2n + sv[j]) - rmx) * rin : 0.f;
        o[j] = (short)f2b(v);
    }
    *(vs8*)(att + (size_t)n * M_ + m) = o;
}

// ---------------- u_in += att @ h1  (B from h1T), K split 8 ways ----------------
__global__ __launch_bounds__(256) void k_gemmA(const unsigned short* __restrict__ att,
                                               const unsigned short* __restrict__ h1T,
                                               float* __restrict__ u_in) {
    int w = threadIdx.x >> 6, l = threadIdx.x & 63;
    int lr = l & 15, lg = l >> 4;
    int nb = blockIdx.x * 32 + (w >> 1) * 16;
    int fb = (w & 1) * 64;
    vf4 acc[4] = {};
    const unsigned short* ap = att + (size_t)(nb + lr) * M_ + lg * 8;
    int m0s = blockIdx.y * (M_ / 8);
    for (int m0 = m0s; m0 < m0s + M_ / 8; m0 += 32) {
        ABu af; af.s = *(const vs8*)(ap + m0);
#pragma unroll
        for (int q = 0; q < 4; ++q) {
            ABu bf; bf.s = *(const vs8*)(h1T + (size_t)(fb + q * 16 + lr) * M_ + m0 + lg * 8);
            acc[q] = mfma16(af, bf, acc[q]);
        }
    }
#pragma unroll
    for (int q = 0; q < 4; ++q)
#pragma unroll
        for (int r = 0; r < 4; ++r)
            atomicAdd(&u_in[(size_t)(blockIdx.x * 32 + (w >> 1) * 16 + lg * 4 + r) * F_ + fb + q * 16 + lr],
                      acc[q][r]);
}

// ---- v_in += att.T @ h2: LDS-transposed att tiles, K split 8 ways ----
__global__ __launch_bounds__(256) void k_gemmB(const unsigned short* __restrict__ att,
                                               const unsigned short* __restrict__ h2T,
                                               float* __restrict__ v_in) {
    __shared__ unsigned short lds[32][34];
    int t = threadIdx.x;
    int w = t >> 6, l = t & 63;
    int lr = l & 15, lg = l >> 4;
    int mb = blockIdx.x * 32;
    int mh = (w >> 1) * 16;
    int fb = (w & 1) * 64;
    int si = t >> 3;
    int sc = (t & 7) * 4;
    vf4 acc[4] = {};
    int n0s = blockIdx.y * (N_ / 8);
    for (int n0 = n0s; n0 < n0s + N_ / 8; n0 += 32) {
        uint2 dv = *(const uint2*)(att + (size_t)(n0 + si) * M_ + mb + sc);
        __syncthreads();
        lds[sc + 0][si] = (unsigned short)(dv.x & 0xffffu);
        lds[sc + 1][si] = (unsigned short)(dv.x >> 16);
        lds[sc + 2][si] = (unsigned short)(dv.y & 0xffffu);
        lds[sc + 3][si] = (unsigned short)(dv.y >> 16);
        __syncthreads();
        ABu af; af.s = *(const vs8*)&lds[mh + lr][lg * 8];
#pragma unroll
        for (int q = 0; q < 4; ++q) {
            ABu bf; bf.s = *(const vs8*)(h2T + (size_t)(fb + q * 16 + lr) * N_ + n0 + lg * 8);
            acc[q] = mfma16(af, bf, acc[q]);
        }
    }
#pragma unroll
    for (int q = 0; q < 4; ++q)
#pragma unroll
        for (int r = 0; r < 4; ++r)
            atomicAdd(&v_in[(size_t)(mb + mh + lg * 4 + r) * F_ + fb + q * 16 + lr], acc[q][r]);
}

// ---- u_in += G @ h2wT^T, G built on the fly from transposed bitmasks; K split 4 ways ----
__global__ __launch_bounds__(256) void k_gemmC3(const uint32_t* __restrict__ BMtc, const uint32_t* __restrict__ BMtp,
                                                const float* __restrict__ w3, const float* __restrict__ w4,
                                                const unsigned short* __restrict__ h2wT,
                                                float* __restrict__ u_in) {
    int w = threadIdx.x >> 6, l = threadIdx.x & 63;
    int lr = l & 15, lg = l >> 4;
    int nb = blockIdx.x * 32 + (w >> 1) * 16;
    int fb = (w & 1) * 64;
    int n = nb + lr;
    int wi = n >> 5;
    int bitpos = n & 31;
    const uint32_t* bc = BMtc + (size_t)wi * B_;
    const uint32_t* bp = BMtp + (size_t)wi * B_;
    vf4 acc[4] = {};
    int b0s = blockIdx.y * (B_ / 4);
    for (int b0 = b0s; b0 < b0s + B_ / 4; b0 += 32) {
        int bb = b0 + lg * 8;
        uint4 c0 = *(const uint4*)(bc + bb);
        uint4 c1 = *(const uint4*)(bc + bb + 4);
        uint4 p0 = *(const uint4*)(bp + bb);
        uint4 p1 = *(const uint4*)(bp + bb + 4);
        float4 wa = *(const float4*)(w3 + bb);
        float4 wb = *(const float4*)(w3 + bb + 4);
        float4 wc = *(const float4*)(w4 + bb);
        float4 wd = *(const float4*)(w4 + bb + 4);
        uint32_t cw[8] = {c0.x, c0.y, c0.z, c0.w, c1.x, c1.y, c1.z, c1.w};
        uint32_t pw[8] = {p0.x, p0.y, p0.z, p0.w, p1.x, p1.y, p1.z, p1.w};
        float w3v[8] = {wa.x, wa.y, wa.z, wa.w, wb.x, wb.y, wb.z, wb.w};
        float w4v[8] = {wc.x, wc.y, wc.z, wc.w, wd.x, wd.y, wd.z, wd.w};
        ABu af;
#pragma unroll
        for (int j = 0; j < 8; ++j) {
            float v = (((cw[j] >> bitpos) & 1u) ? w3v[j] : 0.f) + (((pw[j] >> bitpos) & 1u) ? w4v[j] : 0.f);
            af.s[j] = (short)f2b(v);
        }
#pragma unroll
        for (int q = 0; q < 4; ++q) {
            ABu bf; bf.s = *(const vs8*)(h2wT + (size_t)(fb + q * 16 + lr) * B_ + b0 + lg * 8);
            acc[q] = mfma16(af, bf, acc[q]);
        }
    }
#pragma unroll
    for (int q = 0; q < 4; ++q)
#pragma unroll
        for (int r = 0; r < 4; ++r)
            atomicAdd(&u_in[(size_t)(nb + lg * 4 + r) * F_ + fb + q * 16 + lr], acc[q][r]);
}

// ---------------- batchnorm column stats, both matrices in one launch ----------------
__global__ __launch_bounds__(256) void k_bnstats2(const float* __restrict__ v_in, const float* __restrict__ u_in,
                                                  float* __restrict__ stats) {
    __shared__ float r1[256], r2[256];
    int bx = blockIdx.x;
    const float* P; int R; float* sum; float* sq;
    if (bx < 128) { P = v_in; R = M_; sum = stats;       sq = stats + 128; }
    else          { P = u_in; R = N_; sum = stats + 256; sq = stats + 384; bx -= 128; }
    int f = threadIdx.x & 127;
    int half = threadIdx.x >> 7;
    float s = 0.f, s2v = 0.f;
    for (int r = bx * 2 + half; r < R; r += 256) {
        float v = P[(size_t)r * F_ + f];
        s += v; s2v += v * v;
    }
    r1[threadIdx.x] = s; r2[threadIdx.x] = s2v;
    __syncthreads();
    if (half == 0) {
        atomicAdd(&sum[f], r1[f] + r1[f + 128]);
        atomicAdd(&sq[f], r2[f] + r2[f + 128]);
    }
}

// ---------------- scale/shift from stats ----------------
__global__ void k_bnfinal(const float* __restrict__ stats, const float* __restrict__ g1,
                          const float* __restrict__ b1, const float* __restrict__ g2,
                          const float* __restrict__ b2, float* __restrict__ scsh) {
    int t = threadIdx.x;                                  // 256
    int f = t & 127;
    const float* sum; const float* sq; const float* g; const float* be; float R; float* sc; float* sh;
    if (t < 128) { sum = stats;       sq = stats + 128; g = g1; be = b1; R = 4096.f; sc = scsh;       sh = scsh + 128; }
    else         { sum = stats + 256; sq = stats + 384; g = g2; be = b2; R = 8192.f; sc = scsh + 256; sh = scsh + 384; }
    float mean = sum[f] / R;
    float var = sq[f] / R - mean * mean;
    float s = g[f] * rsqrtf(var + 1e-5f);
    sc[f] = s; sh[f] = be[f] - mean * s;
}

// ---------------- apply bn + leaky + cast bf16, both matrices in one launch ----------------
__global__ void k_bnapply2(const float* __restrict__ v_in, const float* __restrict__ u_in,
                           const float* __restrict__ scsh,
                           unsigned short* __restrict__ v_outb, unsigned short* __restrict__ u_outb) {
    int id = blockIdx.x * 256 + threadIdx.x;
    const float* P; unsigned short* Q; int which, idx;
    if (id < M_ * F_) { P = v_in; Q = v_outb; which = 0; idx = id; }
    else              { P = u_in; Q = u_outb; which = 1; idx = id - M_ * F_; }
    int f = idx & 127;
    float s = scsh[which * 256 + f], sh = scsh[which * 256 + 128 + f];
    Q[idx] = f2b(lrelu(P[idx] * s + sh));
}

// ---------------- out = elu(U @ V^T) ----------------
__global__ __launch_bounds__(256) void k_gemmD(const unsigned short* __restrict__ U,
                                               const unsigned short* __restrict__ V,
                                               float* __restrict__ out) {
    int w = threadIdx.x >> 6, l = threadIdx.x & 63;
    int lr = l & 15, lg = l >> 4;
    int nb = blockIdx.x * 64 + w * 16;
    int mb = blockIdx.y * 64;
    vf4 acc[4] = {};
#pragma unroll
    for (int k0 = 0; k0 < F_; k0 += 32) {
        ABu af; af.s = *(const vs8*)(U + (size_t)(nb + lr) * F_ + k0 + lg * 8);
#pragma unroll
        for (int q = 0; q < 4; ++q) {
            ABu bf; bf.s = *(const vs8*)(V + (size_t)(mb + q * 16 + lr) * F_ + k0 + lg * 8);
            acc[q] = mfma16(af, bf, acc[q]);
        }
    }
#pragma unroll
    for (int q = 0; q < 4; ++q)
#pragma unroll
        for (int r = 0; r < 4; ++r) {
            int row = nb + lg * 4 + r;
            int col = mb + q * 16 + lr;
            float x = acc[q][r];
            out[(size_t)row * M_ + col] = x > 0.f ? x : __expf(x) - 1.f;
        }
}

extern "C" void kernel_launch(void* const* d_in, const int* in_sizes, int n_in,
                              void* d_out, int out_size, void* d_ws, size_t ws_size,
                              hipStream_t stream) {
    const float* Sinput = (const float*)d_in[0];
    const float* Rinput = (const float*)d_in[1];
    const int* inter_adj = (const int*)d_in[2];
    const int* city_adj = (const int*)d_in[3];
    const int* prov_adj = (const int*)d_in[4];
    const int* src = (const int*)d_in[5];
    const float* W1 = (const float*)d_in[6];
    const float* W2 = (const float*)d_in[7];
    const float* a = (const float*)d_in[8];
    const float* g1 = (const float*)d_in[11];
    const float* b1 = (const float*)d_in[12];
    const float* g2 = (const float*)d_in[13];
    const float* b2 = (const float*)d_in[14];
    float* out = (float*)d_out;

    char* ws = (char*)d_ws;
    size_t o = 0;
    auto take = [&](size_t bytes) { char* p = ws + o; o += (bytes + 255) & ~(size_t)255; return p; };
    float* u_in = (float*)take((size_t)N_ * F_ * 4);
    float* v_in = (float*)take((size_t)M_ * F_ * 4);
    float* stats = (float*)take(512 * 4);
    size_t zero_bytes = o;                               // u_in + v_in + stats zeroed each launch
    float* h1 = (float*)take((size_t)M_ * F_ * 4);
    float* h2 = (float*)take((size_t)N_ * F_ * 4);
    unsigned short* h1T = (unsigned short*)take((size_t)F_ * M_ * 2);
    unsigned short* h2T = (unsigned short*)take((size_t)F_ * N_ * 2);
    unsigned short* W1T = (unsigned short*)take((size_t)F_ * FIN_ * 2);
    unsigned short* W2T = (unsigned short*)take((size_t)F_ * FIN_ * 2);
    float* s1 = (float*)take(M_ * 4);
    float* s2 = (float*)take(N_ * 4);
    float* rowmax = (float*)take(N_ * 4);
    float* rowinv = (float*)take(N_ * 4);
    float* w3 = (float*)take(B_ * 4);
    float* w4 = (float*)take(B_ * 4);
    unsigned short* h2wT = (unsigned short*)take((size_t)F_ * B_ * 2);
    float* scsh = (float*)take(512 * 4);
    unsigned short* u_outb = (unsigned short*)take((size_t)N_ * F_ * 2);
    unsigned short* v_outb = (unsigned short*)take((size_t)M_ * F_ * 2);
    uint32_t* BMtc = (uint32_t*)take((size_t)256 * B_ * 4);
    uint32_t* BMtp = (uint32_t*)take((size_t)256 * B_ * 4);
    unsigned short* bm = (unsigned short*)take((size_t)N_ * 256 * 2);
    unsigned short* att = (unsigned short*)take((size_t)N_ * M_ * 2);
    (void)ws_size; (void)in_sizes; (void)n_in; (void)out_size;

    hipMemsetAsync(d_ws, 0, zero_bytes, stream);

    k_wprep<<<256, 256, 0, stream>>>(W1, W2, W1T, W2T);
    k_hgemm2<<<(M_ + N_) / 16, 256, 0, stream>>>(Rinput, Sinput, W1T, W2T, h1, h2);
    k_castT2<<<dim3((M_ + N_) / 32, 4), 256, 0, stream>>>(h1, h2, h1T, h2T);
    k_svecgather<<<(M_ + N_) / 4 + B_ / 2, 256, 0, stream>>>(h1, h2, a, src, s1, s2, h2wT);
    k_adjmask<<<N_ + 2 * B_, 256, 0, stream>>>(inter_adj, s1, s2, bm, rowmax, rowinv,
                                               city_adj, prov_adj, src, BMtc, BMtp, w3, w4);
    k_attmat<<<(size_t)N_ * M_ / 8 / 256, 256, 0, stream>>>((const unsigned char*)bm, s1, s2, rowmax, rowinv, att);
    k_gemmA<<<dim3(N_ / 32, 8), 256, 0, stream>>>(att, h1T, u_in);
    k_gemmB<<<dim3(M_ / 32, 8), 256, 0, stream>>>(att, h2T, v_in);
    k_gemmC3<<<dim3(N_ / 32, 4), 256, 0, stream>>>(BMtc, BMtp, w3, w4, h2wT, u_in);
    k_bnstats2<<<256, 256, 0, stream>>>(v_in, u_in, stats);
    k_bnfinal<<<1, 256, 0, stream>>>(stats, g1, b1, g2, b2, scsh);
    k_bnapply2<<<(M_ + N_) * F_ / 256, 256, 0, stream>>>(v_in, u_in, scsh, v_outb, u_outb);
    k_gemmD<<<dim3(N_ / 64, M_ / 64), 256, 0, stream>>>(u_outb, v_outb, out);
}